// Round 3
// baseline (3872.330 us; speedup 1.0000x reference)
//
#include <hip/hip_runtime.h>
#include <hip/hip_fp16.h>

#define NN 100000          // nodes
#define NC 1024            // communities
#define NM 101024          // NN + NC
#define NE 3200000         // edges
#define DD 128             // feature dim

#define A1CAP 140000       // records per super-bucket region (mean 131072, +25 sigma)
#define A2CAP 4608         // records per 128-row bucket region (mean 4096, +8 sigma)
#define NB 782             // ceil(NN/128) buckets

typedef __attribute__((ext_vector_type(8))) short s16x8;
typedef __attribute__((ext_vector_type(4))) float f32x4;

#define MFMA __builtin_amdgcn_mfma_f32_16x16x32_bf16

__device__ __forceinline__ short f2bf(float f) {
  unsigned u = __float_as_uint(f);
  u = (u + 0x7FFFu + ((u >> 16) & 1u)) >> 16;   // RNE
  return (short)u;
}
__device__ __forceinline__ float bf2f(short h) {
  return __uint_as_float(((unsigned)(unsigned short)h) << 16);
}

// ---------------- zero init (u2acc | colsum contiguous) ----------------
__global__ __launch_bounds__(256) void k_zero(int* __restrict__ p, int n) {
  int t = blockIdx.x * 256 + threadIdx.x;
  if (t < n) p[t] = 0;
}

// ---------------- cursor init ----------------
__global__ __launch_bounds__(1024) void k_cinit(int* __restrict__ cur25,
                                                int* __restrict__ cur800) {
  int t = threadIdx.x;
  if (t < 25) cur25[t] = t * A1CAP;
  if (t < 800) cur800[t] = t * A2CAP;
}

// ------------- pack W into B-fragment layout, split hi/lo bf16 -------------
__global__ __launch_bounds__(256) void k_wpack(const float* __restrict__ W,
                                               short* __restrict__ wh,
                                               short* __restrict__ wl) {
  int t = blockIdx.x * 256 + threadIdx.x;   // 16384
  int k = t >> 7, d = t & 127;
  float v = W[t];
  short h = f2bf(v);
  short l = f2bf(v - bf2f(h));
  int idx = (((k >> 5) * 8 + (d >> 4)) * 64 + ((k >> 3) & 3) * 16 + (d & 15)) * 8 + (k & 7);
  wh[idx] = h;
  wl[idx] = l;
}

// ------------- support = x @ W, split-bf16 (3 MFMA terms ~ fp32) -------------
__global__ __launch_bounds__(256) void k_support(const float* __restrict__ x,
                                                 const short* __restrict__ wh,
                                                 const short* __restrict__ wl,
                                                 float* __restrict__ sup) {
  int wave = threadIdx.x >> 6, lane = threadIdx.x & 63;
  int r0 = blockIdx.x * 64 + wave * 16;
  int arow = r0 + (lane & 15);
  if (arow >= NM) arow = NM - 1;
  int kb = (lane >> 4) * 8;
  f32x4 acc[8];
  #pragma unroll
  for (int dt = 0; dt < 8; ++dt)
    #pragma unroll
    for (int q = 0; q < 4; ++q) acc[dt][q] = 0.f;

  #pragma unroll
  for (int ks = 0; ks < 4; ++ks) {
    const float* ap = x + (size_t)arow * DD + ks * 32 + kb;
    float4 v0 = *(const float4*)ap;
    float4 v1 = *(const float4*)(ap + 4);
    float vv[8] = {v0.x, v0.y, v0.z, v0.w, v1.x, v1.y, v1.z, v1.w};
    s16x8 xh, xl;
    #pragma unroll
    for (int j = 0; j < 8; ++j) {
      short h = f2bf(vv[j]);
      xh[j] = h;
      xl[j] = f2bf(vv[j] - bf2f(h));
    }
    const short* bph = wh + ks * 4096 + lane * 8;
    const short* bpl = wl + ks * 4096 + lane * 8;
    #pragma unroll
    for (int dt = 0; dt < 8; ++dt) {
      s16x8 bh = *(const s16x8*)(bph + dt * 512);
      s16x8 bl = *(const s16x8*)(bpl + dt * 512);
      acc[dt] = MFMA(xh, bh, acc[dt], 0, 0, 0);
      acc[dt] = MFMA(xl, bh, acc[dt], 0, 0, 0);
      acc[dt] = MFMA(xh, bl, acc[dt], 0, 0, 0);
    }
  }
  int rg = (lane >> 4) * 4, cc = lane & 15;
  #pragma unroll
  for (int dt = 0; dt < 8; ++dt)
    #pragma unroll
    for (int q = 0; q < 4; ++q) {
      int rr = r0 + rg + q;
      if (rr < NM) sup[(size_t)rr * DD + dt * 16 + cc] = acc[dt][q];
    }
}

// ------------- fp16 row-major copy of sup_nodes for the SPMM gather -------------
__global__ __launch_bounds__(256) void k_suph(const float* __restrict__ sup,
                                              unsigned* __restrict__ suph) {
  int t = blockIdx.x * 256 + threadIdx.x;   // NN*64
  float2 f = *(const float2*)(sup + (size_t)t * 2);
  __half2 h = __floats2half2_rn(f.x, f.y);
  suph[t] = *(unsigned*)&h;
}

// ------------- pack support rows into bf16 B-fragment layout -------------
__global__ __launch_bounds__(256) void k_spack(const float* __restrict__ sup,
                                               short* __restrict__ bpk) {
  int t = blockIdx.x * 256 + threadIdx.x;   // 1,616,384
  int d = t & 127, ib = t >> 7;             // ib < 12628 (blocks of 8 rows)
  int rb = ib >> 2, g = ib & 3;
  s16x8 o;
  #pragma unroll
  for (int j = 0; j < 8; ++j) o[j] = f2bf(sup[(size_t)(ib * 8 + j) * DD + d]);
  *(s16x8*)(bpk + (size_t)((rb * 8 + (d >> 4)) * 64 + g * 16 + (d & 15)) * 8) = o;
}

// ------------- U1: comm_to_node = (A @ sup_comm) / rowsum -> out[0:NN) -------------
__global__ __launch_bounds__(256) void k_u1(const float* __restrict__ A,
                                            const short* __restrict__ bpk,
                                            float* __restrict__ out) {
  __shared__ float rsh[128];
  int wave = threadIdx.x >> 6, lane = threadIdx.x & 63;
  int r0 = blockIdx.x * 128 + wave * 32;
  int kb = (lane >> 4) * 8;
  f32x4 acc[2][8];
  #pragma unroll
  for (int m = 0; m < 2; ++m)
    #pragma unroll
    for (int dt = 0; dt < 8; ++dt)
      #pragma unroll
      for (int q = 0; q < 4; ++q) acc[m][dt][q] = 0.f;
  float rs[2] = {0.f, 0.f};
  int row[2];
  #pragma unroll
  for (int m = 0; m < 2; ++m) {
    int r = r0 + m * 16 + (lane & 15);
    row[m] = (r < NN) ? r : NN - 1;
  }
  for (int ks = 0; ks < 32; ++ks) {
    s16x8 af[2];
    #pragma unroll
    for (int m = 0; m < 2; ++m) {
      const float* ap = A + (size_t)row[m] * NC + ks * 32 + kb;
      float4 v0 = *(const float4*)ap;
      float4 v1 = *(const float4*)(ap + 4);
      rs[m] += v0.x + v0.y + v0.z + v0.w + v1.x + v1.y + v1.z + v1.w;
      af[m][0] = f2bf(v0.x); af[m][1] = f2bf(v0.y);
      af[m][2] = f2bf(v0.z); af[m][3] = f2bf(v0.w);
      af[m][4] = f2bf(v1.x); af[m][5] = f2bf(v1.y);
      af[m][6] = f2bf(v1.z); af[m][7] = f2bf(v1.w);
    }
    const short* bp = bpk + (size_t)(3125 + ks) * 4096 + lane * 8;
    #pragma unroll
    for (int dt = 0; dt < 8; ++dt) {
      s16x8 b = *(const s16x8*)(bp + dt * 512);
      acc[0][dt] = MFMA(af[0], b, acc[0][dt], 0, 0, 0);
      acc[1][dt] = MFMA(af[1], b, acc[1][dt], 0, 0, 0);
    }
  }
  #pragma unroll
  for (int m = 0; m < 2; ++m) {
    float v = rs[m];
    v += __shfl_xor(v, 16);
    v += __shfl_xor(v, 32);
    if (lane < 16) rsh[wave * 32 + m * 16 + lane] = v;
  }
  __syncthreads();
  int rg = (lane >> 4) * 4, cc = lane & 15;
  #pragma unroll
  for (int m = 0; m < 2; ++m)
    #pragma unroll
    for (int q = 0; q < 4; ++q) {
      int wr = wave * 32 + m * 16 + rg + q;
      int r = blockIdx.x * 128 + wr;
      if (r < NN) {
        float inv = 1.f / rsh[wr];
        #pragma unroll
        for (int dt = 0; dt < 8; ++dt)
          out[(size_t)r * DD + dt * 16 + cc] = acc[m][dt][q] * inv;
      }
    }
}

// ------------- U2 partial: A^T @ sup_nodes (atomic reduce) + colsum partials -------------
__global__ __launch_bounds__(256) void k_u2(const float* __restrict__ A,
                                            const short* __restrict__ bpk,
                                            float* __restrict__ u2,
                                            float* __restrict__ csum) {
  __shared__ short atile[2][128 * 40];   // [c_local][i] bf16, padded pitch 40
  int wave = threadIdx.x >> 6, lane = threadIdx.x & 63;
  int c0 = (blockIdx.x & 7) * 128;
  int s = blockIdx.x >> 3;            // 0..124, i-chunk of 800 rows
  int wc = wave * 32;
  f32x4 acc[2][8];
  #pragma unroll
  for (int m = 0; m < 2; ++m)
    #pragma unroll
    for (int dt = 0; dt < 8; ++dt)
      #pragma unroll
      for (int q = 0; q < 4; ++q) acc[m][dt][q] = 0.f;
  float cs[2] = {0.f, 0.f};
  int ld_i = threadIdx.x >> 5;         // 0..7
  int ld_c = (threadIdx.x & 31) * 4;   // 0..124

  float4 rv[4];
  #pragma unroll
  for (int it = 0; it < 4; ++it)
    rv[it] = *(const float4*)(A + (size_t)(s * 800 + it * 8 + ld_i) * NC + c0 + ld_c);
  #pragma unroll
  for (int it = 0; it < 4; ++it) {
    int i = it * 8 + ld_i;
    atile[0][(ld_c + 0) * 40 + i] = f2bf(rv[it].x);
    atile[0][(ld_c + 1) * 40 + i] = f2bf(rv[it].y);
    atile[0][(ld_c + 2) * 40 + i] = f2bf(rv[it].z);
    atile[0][(ld_c + 3) * 40 + i] = f2bf(rv[it].w);
  }
  __syncthreads();

  for (int kk = 0; kk < 25; ++kk) {
    int p = kk & 1;
    if (kk < 24) {
      int i0n = s * 800 + (kk + 1) * 32;
      #pragma unroll
      for (int it = 0; it < 4; ++it)
        rv[it] = *(const float4*)(A + (size_t)(i0n + it * 8 + ld_i) * NC + c0 + ld_c);
    }
    s16x8 af[2];
    #pragma unroll
    for (int m = 0; m < 2; ++m) {
      af[m] = *(const s16x8*)(&atile[p][(wc + m * 16 + (lane & 15)) * 40 + (lane >> 4) * 8]);
      #pragma unroll
      for (int j = 0; j < 8; ++j) cs[m] += bf2f(af[m][j]);
    }
    if (kk < 24) {
      #pragma unroll
      for (int it = 0; it < 4; ++it) {
        int i = it * 8 + ld_i;
        atile[p ^ 1][(ld_c + 0) * 40 + i] = f2bf(rv[it].x);
        atile[p ^ 1][(ld_c + 1) * 40 + i] = f2bf(rv[it].y);
        atile[p ^ 1][(ld_c + 2) * 40 + i] = f2bf(rv[it].z);
        atile[p ^ 1][(ld_c + 3) * 40 + i] = f2bf(rv[it].w);
      }
    }
    const short* bp = bpk + (size_t)(s * 25 + kk) * 4096 + lane * 8;
    #pragma unroll
    for (int dt = 0; dt < 8; ++dt) {
      s16x8 b = *(const s16x8*)(bp + dt * 512);
      acc[0][dt] = MFMA(af[0], b, acc[0][dt], 0, 0, 0);
      acc[1][dt] = MFMA(af[1], b, acc[1][dt], 0, 0, 0);
    }
    __syncthreads();
  }
  #pragma unroll
  for (int m = 0; m < 2; ++m) {
    float v = cs[m];
    v += __shfl_xor(v, 16);
    v += __shfl_xor(v, 32);
    if (lane < 16) atomicAdd(&csum[c0 + wc + m * 16 + lane], v);
  }
  int rg = (lane >> 4) * 4, cc = lane & 15;
  #pragma unroll
  for (int m = 0; m < 2; ++m)
    #pragma unroll
    for (int dt = 0; dt < 8; ++dt)
      #pragma unroll
      for (int q = 0; q < 4; ++q)
        atomicAdd(&u2[(size_t)(c0 + wc + m * 16 + rg + q) * DD + dt * 16 + cc],
                  acc[m][dt][q]);
}

// ------------- out2 = u2 / colsum -> out[NN:NM) -------------
__global__ __launch_bounds__(256) void k_out2(const float* __restrict__ u2,
                                              const float* __restrict__ csum,
                                              float* __restrict__ out) {
  int t = blockIdx.x * 256 + threadIdx.x;   // 131072
  int c = t >> 7;
  out[(size_t)(NN + c) * DD + (t & 127)] = u2[t] / csum[c];
}

// ------------- A1: bin edges into 25 super-buckets (row>>12), staged flush -------------
__global__ __launch_bounds__(256) void k_a1(const int* __restrict__ er,
                                            const int* __restrict__ ec,
                                            const float* __restrict__ ev,
                                            int* __restrict__ cur25,
                                            int2* __restrict__ a1buf) {
  __shared__ int2 stg[25][320];   // 64000 B
  __shared__ int cnt[25];
  int t = threadIdx.x, wave = t >> 6, lane = t & 63;
  int beg = blockIdx.x * 6250, end = beg + 6250;   // NE = 512*6250
  if (t < 25) cnt[t] = 0;
  __syncthreads();
  for (int b0 = beg; b0 < end; b0 += 256) {
    int e = b0 + t;
    if (e < end) {
      int row = er[e];
      int2 rec = make_int2(ec[e] | ((row & 4095) << 17), __float_as_int(ev[e]));
      int s = row >> 12;
      int slot = atomicAdd(&cnt[s], 1);
      stg[s][slot] = rec;
    }
    __syncthreads();
    for (int s = wave; s < 25; s += 4) {
      int c = cnt[s];
      if (c >= 64) {
        int pos;
        if (lane == 0) pos = atomicAdd(&cur25[s], c);
        pos = __shfl(pos, 0);
        for (int i = lane; i < c; i += 64) a1buf[pos + i] = stg[s][i];
        if (lane == 0) cnt[s] = 0;
      }
    }
    __syncthreads();
  }
  for (int s = wave; s < 25; s += 4) {   // drain
    int c = cnt[s];
    if (c > 0) {
      int pos;
      if (lane == 0) pos = atomicAdd(&cur25[s], c);
      pos = __shfl(pos, 0);
      for (int i = lane; i < c; i += 64) a1buf[pos + i] = stg[s][i];
    }
  }
}

// ------------- A2: bin each super into 32 sub-buckets of 128 rows -------------
__global__ __launch_bounds__(128) void k_a2(const int2* __restrict__ a1buf,
                                            const int* __restrict__ cur25,
                                            int* __restrict__ cur800,
                                            int2* __restrict__ a2buf) {
  __shared__ int2 stg[32][255];   // 65280 B
  __shared__ int cnt[32];
  int t = threadIdx.x, wave = t >> 6, lane = t & 63;
  int s = blockIdx.x >> 6, j = blockIdx.x & 63;   // 25 supers x 64 blocks
  int total = cur25[s] - s * A1CAP;
  int chunk = (total + 63) >> 6;
  int beg = j * chunk, end = min(total, beg + chunk);
  const int2* rp = a1buf + (size_t)s * A1CAP;
  if (t < 32) cnt[t] = 0;
  __syncthreads();
  for (int b0 = beg; b0 < end; b0 += 128) {
    int e = b0 + t;
    if (e < end) {
      int2 rec = rp[e];
      int sub = (rec.x >> 24) & 31;
      int slot = atomicAdd(&cnt[sub], 1);
      stg[sub][slot] = rec;
    }
    __syncthreads();
    for (int sub = wave * 16; sub < wave * 16 + 16; ++sub) {
      int c = cnt[sub];
      if (c >= 128) {
        int pos;
        if (lane == 0) pos = atomicAdd(&cur800[(s << 5) + sub], c);
        pos = __shfl(pos, 0);
        for (int i = lane; i < c; i += 64) a2buf[pos + i] = stg[sub][i];
        if (lane == 0) cnt[sub] = 0;
      }
    }
    __syncthreads();
  }
  for (int sub = wave * 16; sub < wave * 16 + 16; ++sub) {   // drain
    int c = cnt[sub];
    if (c > 0) {
      int pos;
      if (lane == 0) pos = atomicAdd(&cur800[(s << 5) + sub], c);
      pos = __shfl(pos, 0);
      for (int i = lane; i < c; i += 64) a2buf[pos + i] = stg[sub][i];
    }
  }
}

// ------------- B: SPMM per (128-row bucket, 64-col half), LDS f32 accum -------------
__global__ __launch_bounds__(256) void k_b(const int2* __restrict__ a2buf,
                                           const int* __restrict__ cur800,
                                           const unsigned short* __restrict__ suphh,
                                           float* __restrict__ out) {
  __shared__ float acc[128 * 64];   // 32 KB
  int t = threadIdx.x, wave = t >> 6, lane = t & 63;
  int b = blockIdx.x >> 1, h = blockIdx.x & 1;
  int cntb = cur800[b] - b * A2CAP;
  const int2* rp = a2buf + (size_t)b * A2CAP;
  #pragma unroll
  for (int i = 0; i < 32; ++i) acc[i * 256 + t] = 0.f;
  __syncthreads();

  for (int b0 = wave * 64; b0 < cntb; b0 += 256) {
    int idx = b0 + lane;
    int2 rec = rp[min(idx, cntb - 1)];
    if (idx >= cntb) rec.y = 0;   // val = 0 padding -> harmless adds
    for (int j = 0; j < 64; j += 8) {
      unsigned short g[8];
      float vals[8];
      int rls[8];
      #pragma unroll
      for (int u = 0; u < 8; ++u) {
        int rx = __shfl(rec.x, j + u);
        int ry = __shfl(rec.y, j + u);
        vals[u] = __int_as_float(ry);
        rls[u] = (rx >> 17) & 127;
        g[u] = suphh[(size_t)(rx & 0x1FFFF) * 128 + (h << 6) + lane];
      }
      #pragma unroll
      for (int u = 0; u < 8; ++u) {
        __half hv = *reinterpret_cast<__half*>(&g[u]);
        atomicAdd(&acc[rls[u] * 64 + lane], __half2float(hv) * vals[u]);
      }
    }
  }
  __syncthreads();
  int col = t & 63, rg = t >> 6;
  #pragma unroll 4
  for (int rr = 0; rr < 32; ++rr) {
    int row = b * 128 + rg * 32 + rr;
    if (row < NN) {
      size_t o = (size_t)row * 128 + (h << 6) + col;
      out[o] += acc[(rg * 32 + rr) * 64 + col];
    }
  }
}

extern "C" void kernel_launch(void* const* d_in, const int* in_sizes, int n_in,
                              void* d_out, int out_size, void* d_ws, size_t ws_size,
                              hipStream_t stream) {
  const float* x  = (const float*)d_in[0];
  const float* W  = (const float*)d_in[1];
  const float* A  = (const float*)d_in[2];
  const int*   er = (const int*)d_in[3];
  const int*   ec = (const int*)d_in[4];
  const float* ev = (const float*)d_in[5];
  float* out = (float*)d_out;

  char* ws = (char*)d_ws;
  size_t off = 0;
  auto alloc = [&](size_t bytes) -> void* {
    off = (off + 255) & ~(size_t)255;
    void* p = ws + off;
    off += bytes;
    return p;
  };
  float*    sup   = (float*)alloc((size_t)NM * DD * 4);     // 51.7 MB
  short*    bpk   = (short*)alloc((size_t)NM * DD * 2);     // 25.9 MB
  unsigned* suphp = (unsigned*)alloc((size_t)NN * 64 * 4);  // 25.6 MB fp16 nodes
  short*    wh    = (short*)alloc(128 * 128 * 2);
  short*    wl    = (short*)alloc(128 * 128 * 2);
  // zero region (contiguous): u2acc | colsum
  float* u2    = (float*)alloc((size_t)NC * DD * 4);        // 131072 f
  float* csum  = (float*)alloc(NC * 4);                     // 1024 f
  int*   cur25 = (int*)alloc(25 * 4);
  int*   cur800= (int*)alloc(800 * 4);
  int2*  a1buf = (int2*)alloc((size_t)25 * A1CAP * 8);      // 28.0 MB
  int2*  a2buf = (int2*)alloc((size_t)800 * A2CAP * 8);     // 29.5 MB
  (void)ws_size; (void)in_sizes; (void)n_in; (void)out_size;

  const int ZN = NC * DD + NC;   // u2 | csum contiguous
  k_zero<<<dim3((ZN + 255) / 256), dim3(256), 0, stream>>>((int*)u2, ZN);
  k_cinit<<<dim3(1), dim3(1024), 0, stream>>>(cur25, cur800);
  k_wpack<<<dim3(64), dim3(256), 0, stream>>>(W, wh, wl);
  k_support<<<dim3(1579), dim3(256), 0, stream>>>(x, wh, wl, sup);
  k_suph<<<dim3(25000), dim3(256), 0, stream>>>(sup, suphp);
  k_spack<<<dim3(6314), dim3(256), 0, stream>>>(sup, bpk);
  k_a1<<<dim3(512), dim3(256), 0, stream>>>(er, ec, ev, cur25, a1buf);
  k_a2<<<dim3(1600), dim3(128), 0, stream>>>(a1buf, cur25, cur800, a2buf);
  k_u1<<<dim3(782), dim3(256), 0, stream>>>(A, bpk, out);
  k_u2<<<dim3(1000), dim3(256), 0, stream>>>(A, bpk, u2, csum);
  k_out2<<<dim3(512), dim3(256), 0, stream>>>(u2, csum, out);
  k_b<<<dim3(NB * 2), dim3(256), 0, stream>>>(a2buf, cur800, (const unsigned short*)suphp, out);
}

// Round 4
// 1610.852 us; speedup vs baseline: 2.4039x; 2.4039x over previous
//
#include <hip/hip_runtime.h>
#include <hip/hip_fp16.h>

#define NN 100000          // nodes
#define NC 1024            // communities
#define NM 101024          // NN + NC
#define NE 3200000         // edges
#define DD 128             // feature dim

#define A1CAP 140000       // records per super-bucket region (mean 128000, +30 sigma)

typedef __attribute__((ext_vector_type(8))) short s16x8;
typedef __attribute__((ext_vector_type(4))) float f32x4;

#define MFMA __builtin_amdgcn_mfma_f32_16x16x32_bf16

__device__ __forceinline__ short f2bf(float f) {
  unsigned u = __float_as_uint(f);
  u = (u + 0x7FFFu + ((u >> 16) & 1u)) >> 16;   // RNE
  return (short)u;
}
__device__ __forceinline__ float bf2f(short h) {
  return __uint_as_float(((unsigned)(unsigned short)h) << 16);
}

// ---------------- zero init (u2acc | colsum | hist contiguous) ----------------
__global__ __launch_bounds__(256) void k_zero(int* __restrict__ p, int n) {
  int t = blockIdx.x * 256 + threadIdx.x;
  if (t < n) p[t] = 0;
}

// ---------------- cursor init ----------------
__global__ __launch_bounds__(64) void k_cinit(int* __restrict__ cur25) {
  int t = threadIdx.x;
  if (t < 25) cur25[t] = t * A1CAP;
}

// ------------- pack W into B-fragment layout, split hi/lo bf16 -------------
__global__ __launch_bounds__(256) void k_wpack(const float* __restrict__ W,
                                               short* __restrict__ wh,
                                               short* __restrict__ wl) {
  int t = blockIdx.x * 256 + threadIdx.x;   // 16384
  int k = t >> 7, d = t & 127;
  float v = W[t];
  short h = f2bf(v);
  short l = f2bf(v - bf2f(h));
  int idx = (((k >> 5) * 8 + (d >> 4)) * 64 + ((k >> 3) & 3) * 16 + (d & 15)) * 8 + (k & 7);
  wh[idx] = h;
  wl[idx] = l;
}

// ------------- support = x @ W, split-bf16 (3 MFMA terms ~ fp32) -------------
__global__ __launch_bounds__(256) void k_support(const float* __restrict__ x,
                                                 const short* __restrict__ wh,
                                                 const short* __restrict__ wl,
                                                 float* __restrict__ sup) {
  int wave = threadIdx.x >> 6, lane = threadIdx.x & 63;
  int r0 = blockIdx.x * 64 + wave * 16;
  int arow = r0 + (lane & 15);
  if (arow >= NM) arow = NM - 1;
  int kb = (lane >> 4) * 8;
  f32x4 acc[8];
  #pragma unroll
  for (int dt = 0; dt < 8; ++dt)
    #pragma unroll
    for (int q = 0; q < 4; ++q) acc[dt][q] = 0.f;

  #pragma unroll
  for (int ks = 0; ks < 4; ++ks) {
    const float* ap = x + (size_t)arow * DD + ks * 32 + kb;
    float4 v0 = *(const float4*)ap;
    float4 v1 = *(const float4*)(ap + 4);
    float vv[8] = {v0.x, v0.y, v0.z, v0.w, v1.x, v1.y, v1.z, v1.w};
    s16x8 xh, xl;
    #pragma unroll
    for (int j = 0; j < 8; ++j) {
      short h = f2bf(vv[j]);
      xh[j] = h;
      xl[j] = f2bf(vv[j] - bf2f(h));
    }
    const short* bph = wh + ks * 4096 + lane * 8;
    const short* bpl = wl + ks * 4096 + lane * 8;
    #pragma unroll
    for (int dt = 0; dt < 8; ++dt) {
      s16x8 bh = *(const s16x8*)(bph + dt * 512);
      s16x8 bl = *(const s16x8*)(bpl + dt * 512);
      acc[dt] = MFMA(xh, bh, acc[dt], 0, 0, 0);
      acc[dt] = MFMA(xl, bh, acc[dt], 0, 0, 0);
      acc[dt] = MFMA(xh, bl, acc[dt], 0, 0, 0);
    }
  }
  int rg = (lane >> 4) * 4, cc = lane & 15;
  #pragma unroll
  for (int dt = 0; dt < 8; ++dt)
    #pragma unroll
    for (int q = 0; q < 4; ++q) {
      int rr = r0 + rg + q;
      if (rr < NM) sup[(size_t)rr * DD + dt * 16 + cc] = acc[dt][q];
    }
}

// ------------- fp16 row-major copy of sup_nodes for the SPMM gather -------------
__global__ __launch_bounds__(256) void k_suph(const float* __restrict__ sup,
                                              unsigned* __restrict__ suph) {
  int t = blockIdx.x * 256 + threadIdx.x;   // NN*64
  float2 f = *(const float2*)(sup + (size_t)t * 2);
  __half2 h = __floats2half2_rn(f.x, f.y);
  suph[t] = *(unsigned*)&h;
}

// ------------- pack support rows into bf16 B-fragment layout -------------
__global__ __launch_bounds__(256) void k_spack(const float* __restrict__ sup,
                                               short* __restrict__ bpk) {
  int t = blockIdx.x * 256 + threadIdx.x;   // 1,616,384
  int d = t & 127, ib = t >> 7;             // ib < 12628 (blocks of 8 rows)
  int rb = ib >> 2, g = ib & 3;
  s16x8 o;
  #pragma unroll
  for (int j = 0; j < 8; ++j) o[j] = f2bf(sup[(size_t)(ib * 8 + j) * DD + d]);
  *(s16x8*)(bpk + (size_t)((rb * 8 + (d >> 4)) * 64 + g * 16 + (d & 15)) * 8) = o;
}

// ------------- U1: comm_to_node = (A @ sup_comm) / rowsum -> out[0:NN) -------------
__global__ __launch_bounds__(256) void k_u1(const float* __restrict__ A,
                                            const short* __restrict__ bpk,
                                            float* __restrict__ out) {
  __shared__ float rsh[128];
  int wave = threadIdx.x >> 6, lane = threadIdx.x & 63;
  int r0 = blockIdx.x * 128 + wave * 32;
  int kb = (lane >> 4) * 8;
  f32x4 acc[2][8];
  #pragma unroll
  for (int m = 0; m < 2; ++m)
    #pragma unroll
    for (int dt = 0; dt < 8; ++dt)
      #pragma unroll
      for (int q = 0; q < 4; ++q) acc[m][dt][q] = 0.f;
  float rs[2] = {0.f, 0.f};
  int row[2];
  #pragma unroll
  for (int m = 0; m < 2; ++m) {
    int r = r0 + m * 16 + (lane & 15);
    row[m] = (r < NN) ? r : NN - 1;
  }
  for (int ks = 0; ks < 32; ++ks) {
    s16x8 af[2];
    #pragma unroll
    for (int m = 0; m < 2; ++m) {
      const float* ap = A + (size_t)row[m] * NC + ks * 32 + kb;
      float4 v0 = *(const float4*)ap;
      float4 v1 = *(const float4*)(ap + 4);
      rs[m] += v0.x + v0.y + v0.z + v0.w + v1.x + v1.y + v1.z + v1.w;
      af[m][0] = f2bf(v0.x); af[m][1] = f2bf(v0.y);
      af[m][2] = f2bf(v0.z); af[m][3] = f2bf(v0.w);
      af[m][4] = f2bf(v1.x); af[m][5] = f2bf(v1.y);
      af[m][6] = f2bf(v1.z); af[m][7] = f2bf(v1.w);
    }
    const short* bp = bpk + (size_t)(3125 + ks) * 4096 + lane * 8;
    #pragma unroll
    for (int dt = 0; dt < 8; ++dt) {
      s16x8 b = *(const s16x8*)(bp + dt * 512);
      acc[0][dt] = MFMA(af[0], b, acc[0][dt], 0, 0, 0);
      acc[1][dt] = MFMA(af[1], b, acc[1][dt], 0, 0, 0);
    }
  }
  #pragma unroll
  for (int m = 0; m < 2; ++m) {
    float v = rs[m];
    v += __shfl_xor(v, 16);
    v += __shfl_xor(v, 32);
    if (lane < 16) rsh[wave * 32 + m * 16 + lane] = v;
  }
  __syncthreads();
  int rg = (lane >> 4) * 4, cc = lane & 15;
  #pragma unroll
  for (int m = 0; m < 2; ++m)
    #pragma unroll
    for (int q = 0; q < 4; ++q) {
      int wr = wave * 32 + m * 16 + rg + q;
      int r = blockIdx.x * 128 + wr;
      if (r < NN) {
        float inv = 1.f / rsh[wr];
        #pragma unroll
        for (int dt = 0; dt < 8; ++dt)
          out[(size_t)r * DD + dt * 16 + cc] = acc[m][dt][q] * inv;
      }
    }
}

// ------------- U2 partial: A^T @ sup_nodes (atomic reduce) + colsum partials -------------
__global__ __launch_bounds__(256) void k_u2(const float* __restrict__ A,
                                            const short* __restrict__ bpk,
                                            float* __restrict__ u2,
                                            float* __restrict__ csum) {
  __shared__ short atile[2][128 * 40];   // [c_local][i] bf16, padded pitch 40
  int wave = threadIdx.x >> 6, lane = threadIdx.x & 63;
  int c0 = (blockIdx.x & 7) * 128;
  int s = blockIdx.x >> 3;            // 0..124, i-chunk of 800 rows
  int wc = wave * 32;
  f32x4 acc[2][8];
  #pragma unroll
  for (int m = 0; m < 2; ++m)
    #pragma unroll
    for (int dt = 0; dt < 8; ++dt)
      #pragma unroll
      for (int q = 0; q < 4; ++q) acc[m][dt][q] = 0.f;
  float cs[2] = {0.f, 0.f};
  int ld_i = threadIdx.x >> 5;         // 0..7
  int ld_c = (threadIdx.x & 31) * 4;   // 0..124

  float4 rv[4];
  #pragma unroll
  for (int it = 0; it < 4; ++it)
    rv[it] = *(const float4*)(A + (size_t)(s * 800 + it * 8 + ld_i) * NC + c0 + ld_c);
  #pragma unroll
  for (int it = 0; it < 4; ++it) {
    int i = it * 8 + ld_i;
    atile[0][(ld_c + 0) * 40 + i] = f2bf(rv[it].x);
    atile[0][(ld_c + 1) * 40 + i] = f2bf(rv[it].y);
    atile[0][(ld_c + 2) * 40 + i] = f2bf(rv[it].z);
    atile[0][(ld_c + 3) * 40 + i] = f2bf(rv[it].w);
  }
  __syncthreads();

  for (int kk = 0; kk < 25; ++kk) {
    int p = kk & 1;
    if (kk < 24) {
      int i0n = s * 800 + (kk + 1) * 32;
      #pragma unroll
      for (int it = 0; it < 4; ++it)
        rv[it] = *(const float4*)(A + (size_t)(i0n + it * 8 + ld_i) * NC + c0 + ld_c);
    }
    s16x8 af[2];
    #pragma unroll
    for (int m = 0; m < 2; ++m) {
      af[m] = *(const s16x8*)(&atile[p][(wc + m * 16 + (lane & 15)) * 40 + (lane >> 4) * 8]);
      #pragma unroll
      for (int j = 0; j < 8; ++j) cs[m] += bf2f(af[m][j]);
    }
    if (kk < 24) {
      #pragma unroll
      for (int it = 0; it < 4; ++it) {
        int i = it * 8 + ld_i;
        atile[p ^ 1][(ld_c + 0) * 40 + i] = f2bf(rv[it].x);
        atile[p ^ 1][(ld_c + 1) * 40 + i] = f2bf(rv[it].y);
        atile[p ^ 1][(ld_c + 2) * 40 + i] = f2bf(rv[it].z);
        atile[p ^ 1][(ld_c + 3) * 40 + i] = f2bf(rv[it].w);
      }
    }
    const short* bp = bpk + (size_t)(s * 25 + kk) * 4096 + lane * 8;
    #pragma unroll
    for (int dt = 0; dt < 8; ++dt) {
      s16x8 b = *(const s16x8*)(bp + dt * 512);
      acc[0][dt] = MFMA(af[0], b, acc[0][dt], 0, 0, 0);
      acc[1][dt] = MFMA(af[1], b, acc[1][dt], 0, 0, 0);
    }
    __syncthreads();
  }
  #pragma unroll
  for (int m = 0; m < 2; ++m) {
    float v = cs[m];
    v += __shfl_xor(v, 16);
    v += __shfl_xor(v, 32);
    if (lane < 16) atomicAdd(&csum[c0 + wc + m * 16 + lane], v);
  }
  int rg = (lane >> 4) * 4, cc = lane & 15;
  #pragma unroll
  for (int m = 0; m < 2; ++m)
    #pragma unroll
    for (int dt = 0; dt < 8; ++dt)
      #pragma unroll
      for (int q = 0; q < 4; ++q)
        atomicAdd(&u2[(size_t)(c0 + wc + m * 16 + rg + q) * DD + dt * 16 + cc],
                  acc[m][dt][q]);
}

// ------------- out2 = u2 / colsum -> out[NN:NM) -------------
__global__ __launch_bounds__(256) void k_out2(const float* __restrict__ u2,
                                              const float* __restrict__ csum,
                                              float* __restrict__ out) {
  int t = blockIdx.x * 256 + threadIdx.x;   // 131072
  int c = t >> 7;
  out[(size_t)(NN + c) * DD + (t & 127)] = u2[t] / csum[c];
}

// ------------- A1: bin edges into 25 super-buckets (row>>12), staged flush.
//               Row histogram fused in. -------------
__global__ __launch_bounds__(256) void k_a1(const int* __restrict__ er,
                                            const int* __restrict__ ec,
                                            const float* __restrict__ ev,
                                            int* __restrict__ cur25,
                                            int2* __restrict__ a1buf,
                                            int* __restrict__ hist) {
  __shared__ int2 stg[25][320];   // 64000 B
  __shared__ int cnt[25];
  int t = threadIdx.x, wave = t >> 6, lane = t & 63;
  int beg = blockIdx.x * 6250, end = beg + 6250;   // NE = 512*6250
  if (t < 25) cnt[t] = 0;
  __syncthreads();
  for (int b0 = beg; b0 < end; b0 += 256) {
    int e = b0 + t;
    if (e < end) {
      int row = er[e];
      atomicAdd(&hist[row], 1);
      int2 rec = make_int2(ec[e] | ((row & 4095) << 17), __float_as_int(ev[e]));
      int s = row >> 12;
      int slot = atomicAdd(&cnt[s], 1);
      stg[s][slot] = rec;
    }
    __syncthreads();
    for (int s = wave; s < 25; s += 4) {
      int c = cnt[s];
      if (c >= 64) {
        int pos;
        if (lane == 0) pos = atomicAdd(&cur25[s], c);
        pos = __shfl(pos, 0);
        for (int i = lane; i < c; i += 64) a1buf[pos + i] = stg[s][i];
        if (lane == 0) cnt[s] = 0;
      }
    }
    __syncthreads();
  }
  for (int s = wave; s < 25; s += 4) {   // drain
    int c = cnt[s];
    if (c > 0) {
      int pos;
      if (lane == 0) pos = atomicAdd(&cur25[s], c);
      pos = __shfl(pos, 0);
      for (int i = lane; i < c; i += 64) a1buf[pos + i] = stg[s][i];
    }
  }
}

// ------------- scans (hist -> exclusive offsets) -------------
__global__ __launch_bounds__(256) void k_scan1(const int* __restrict__ hist,
                                               int* __restrict__ excl,
                                               int* __restrict__ bsum) {
  __shared__ int sm[256];
  int t = threadIdx.x, g = blockIdx.x * 256 + t;
  int v = (g < NN) ? hist[g] : 0;
  sm[t] = v;
  __syncthreads();
  for (int off = 1; off < 256; off <<= 1) {
    int u = (t >= off) ? sm[t - off] : 0;
    __syncthreads();
    sm[t] += u;
    __syncthreads();
  }
  if (g < NN) excl[g] = sm[t] - v;
  if (t == 255) bsum[blockIdx.x] = sm[255];
}

__global__ __launch_bounds__(512) void k_scan2(const int* __restrict__ bsum,
                                               int* __restrict__ boff, int nb) {
  __shared__ int sm[512];
  int t = threadIdx.x;
  int v = (t < nb) ? bsum[t] : 0;
  sm[t] = v;
  __syncthreads();
  for (int off = 1; off < 512; off <<= 1) {
    int u = (t >= off) ? sm[t - off] : 0;
    __syncthreads();
    sm[t] += u;
    __syncthreads();
  }
  if (t < nb) boff[t] = sm[t] - v;
}

__global__ __launch_bounds__(256) void k_scan3(const int* __restrict__ excl,
                                               const int* __restrict__ boff,
                                               int* __restrict__ offs) {
  int t = threadIdx.x, g = blockIdx.x * 256 + t;
  if (g < NN) offs[g] = excl[g] + boff[blockIdx.x];
  if (g == 0) offs[NN] = NE;
}

// ------------- S2: exact CSR scatter, one block per super-bucket.
//               Each block owns a disjoint ~1MB pairs window -> stays in its
//               XCD's L2; every output line written back to HBM once. -------------
__global__ __launch_bounds__(1024) void k_s2(const int2* __restrict__ a1buf,
                                             const int* __restrict__ cur25,
                                             const int* __restrict__ offs,
                                             int2* __restrict__ pairs) {
  __shared__ int cur[4096];
  int t = threadIdx.x;
  int s = blockIdx.x;
  int rbase = s << 12;
  #pragma unroll
  for (int i = 0; i < 4; ++i) {
    int r = rbase + i * 1024 + t;
    cur[i * 1024 + t] = (r < NN) ? offs[r] : 0;
  }
  __syncthreads();
  int total = cur25[s] - s * A1CAP;
  const int2* rp = a1buf + (size_t)s * A1CAP;
  for (int e = t; e < total; e += 1024) {
    int2 rec = rp[e];
    int rl = (rec.x >> 17) & 4095;
    int pos = atomicAdd(&cur[rl], 1);
    pairs[pos] = make_int2(rec.x & 0x1FFFF, rec.y);
  }
}

// ------------- SPMM: one wave per row, fp16 gather, unrolled x4 -------------
__global__ __launch_bounds__(256) void k_spmm(const int* __restrict__ offs,
                                              const int2* __restrict__ pairs,
                                              const unsigned* __restrict__ suph,
                                              float* __restrict__ out) {
  int wave = threadIdx.x >> 6, lane = threadIdx.x & 63;
  int row = blockIdx.x * 4 + wave;   // grid 25000 -> rows exactly cover NN
  int beg = offs[row], end = offs[row + 1];
  float ax = 0.f, ay = 0.f;
  int e = beg;
  for (; e + 4 <= end; e += 4) {
    int2 p0 = pairs[e], p1 = pairs[e + 1], p2 = pairs[e + 2], p3 = pairs[e + 3];
    unsigned g0 = suph[(size_t)p0.x * 64 + lane];
    unsigned g1 = suph[(size_t)p1.x * 64 + lane];
    unsigned g2 = suph[(size_t)p2.x * 64 + lane];
    unsigned g3 = suph[(size_t)p3.x * 64 + lane];
    float2 v0 = __half22float2(*(__half2*)&g0);
    float2 v1 = __half22float2(*(__half2*)&g1);
    float2 v2 = __half22float2(*(__half2*)&g2);
    float2 v3 = __half22float2(*(__half2*)&g3);
    float c0 = __int_as_float(p0.y), c1 = __int_as_float(p1.y);
    float c2 = __int_as_float(p2.y), c3 = __int_as_float(p3.y);
    ax = fmaf(c0, v0.x, ax); ay = fmaf(c0, v0.y, ay);
    ax = fmaf(c1, v1.x, ax); ay = fmaf(c1, v1.y, ay);
    ax = fmaf(c2, v2.x, ax); ay = fmaf(c2, v2.y, ay);
    ax = fmaf(c3, v3.x, ax); ay = fmaf(c3, v3.y, ay);
  }
  for (; e < end; ++e) {
    int2 p = pairs[e];
    unsigned g = suph[(size_t)p.x * 64 + lane];
    float2 v = __half22float2(*(__half2*)&g);
    float c = __int_as_float(p.y);
    ax = fmaf(c, v.x, ax);
    ay = fmaf(c, v.y, ay);
  }
  float2* o = (float2*)(out + (size_t)row * DD);
  float2 c = o[lane];
  c.x += ax;
  c.y += ay;
  o[lane] = c;
}

extern "C" void kernel_launch(void* const* d_in, const int* in_sizes, int n_in,
                              void* d_out, int out_size, void* d_ws, size_t ws_size,
                              hipStream_t stream) {
  const float* x  = (const float*)d_in[0];
  const float* W  = (const float*)d_in[1];
  const float* A  = (const float*)d_in[2];
  const int*   er = (const int*)d_in[3];
  const int*   ec = (const int*)d_in[4];
  const float* ev = (const float*)d_in[5];
  float* out = (float*)d_out;

  char* ws = (char*)d_ws;
  size_t off = 0;
  auto alloc = [&](size_t bytes) -> void* {
    off = (off + 255) & ~(size_t)255;
    void* p = ws + off;
    off += bytes;
    return p;
  };
  float*    sup   = (float*)alloc((size_t)NM * DD * 4);     // 51.7 MB
  short*    bpk   = (short*)alloc((size_t)NM * DD * 2);     // 25.9 MB
  unsigned* suphp = (unsigned*)alloc((size_t)NN * 64 * 4);  // 25.6 MB fp16 nodes
  short*    wh    = (short*)alloc(128 * 128 * 2);
  short*    wl    = (short*)alloc(128 * 128 * 2);
  // zero region (contiguous): u2acc | colsum | hist
  float* u2    = (float*)alloc((size_t)NC * DD * 4);        // 131072 f
  float* csum  = (float*)alloc(NC * 4);                     // 1024 f
  int*   hist  = (int*)alloc(NN * 4);                       // 100000 i
  int*   excl  = (int*)alloc(NN * 4);
  int*   offs  = (int*)alloc((NN + 1) * 4);
  int*   bsum  = (int*)alloc(512 * 4);
  int*   boff  = (int*)alloc(512 * 4);
  int*   cur25 = (int*)alloc(25 * 4);
  int2*  a1buf = (int2*)alloc((size_t)25 * A1CAP * 8);      // 28.0 MB
  int2*  pairs = (int2*)alloc((size_t)NE * 8);              // 25.6 MB
  (void)ws_size; (void)in_sizes; (void)n_in; (void)out_size;

  const int ZN = NC * DD + NC + NN;   // u2 | csum | hist contiguous
  k_zero<<<dim3((ZN + 255) / 256), dim3(256), 0, stream>>>((int*)u2, ZN);
  k_cinit<<<dim3(1), dim3(64), 0, stream>>>(cur25);
  k_wpack<<<dim3(64), dim3(256), 0, stream>>>(W, wh, wl);
  k_support<<<dim3(1579), dim3(256), 0, stream>>>(x, wh, wl, sup);
  k_suph<<<dim3(25000), dim3(256), 0, stream>>>(sup, suphp);
  k_spack<<<dim3(6314), dim3(256), 0, stream>>>(sup, bpk);
  k_a1<<<dim3(512), dim3(256), 0, stream>>>(er, ec, ev, cur25, a1buf, hist);
  k_scan1<<<dim3(391), dim3(256), 0, stream>>>(hist, excl, bsum);
  k_scan2<<<dim3(1), dim3(512), 0, stream>>>(bsum, boff, 391);
  k_scan3<<<dim3(391), dim3(256), 0, stream>>>(excl, boff, offs);
  k_s2<<<dim3(25), dim3(1024), 0, stream>>>(a1buf, cur25, offs, pairs);
  k_u1<<<dim3(782), dim3(256), 0, stream>>>(A, bpk, out);
  k_u2<<<dim3(1000), dim3(256), 0, stream>>>(A, bpk, u2, csum);
  k_out2<<<dim3(512), dim3(256), 0, stream>>>(u2, csum, out);
  k_spmm<<<dim3(25000), dim3(256), 0, stream>>>(offs, pairs, suphp, out);
}

// Round 8
// 1388.445 us; speedup vs baseline: 2.7890x; 1.1602x over previous
//
#include <hip/hip_runtime.h>
#include <hip/hip_fp16.h>

#define NN 100000          // nodes
#define NC 1024            // communities
#define NM 101024          // NN + NC
#define NE 3200000         // edges
#define DD 128             // feature dim

#define SB 49              // super-buckets (2048 rows each, row >> 11)
#define BCAP 120           // per-(block,super) record cap (mean 64, sigma 7.9 -> 7 sigma)
#define A1BLKS 1024        // binning blocks, 3125 edges each

typedef __attribute__((ext_vector_type(8))) short s16x8;
typedef __attribute__((ext_vector_type(4))) float f32x4;

#define MFMA __builtin_amdgcn_mfma_f32_16x16x32_bf16

__device__ __forceinline__ short f2bf(float f) {
  unsigned u = __float_as_uint(f);
  u = (u + 0x7FFFu + ((u >> 16) & 1u)) >> 16;   // RNE
  return (short)u;
}
__device__ __forceinline__ float bf2f(short h) {
  return __uint_as_float(((unsigned)(unsigned short)h) << 16);
}

// ---------------- zero init (u2acc | colsum contiguous) ----------------
__global__ __launch_bounds__(256) void k_zero(int* __restrict__ p, int n) {
  int t = blockIdx.x * 256 + threadIdx.x;
  if (t < n) p[t] = 0;
}

// ------------- pack W into B-fragment layout, split hi/lo bf16 -------------
__global__ __launch_bounds__(256) void k_wpack(const float* __restrict__ W,
                                               short* __restrict__ wh,
                                               short* __restrict__ wl) {
  int t = blockIdx.x * 256 + threadIdx.x;   // 16384
  int k = t >> 7, d = t & 127;
  float v = W[t];
  short h = f2bf(v);
  short l = f2bf(v - bf2f(h));
  int idx = (((k >> 5) * 8 + (d >> 4)) * 64 + ((k >> 3) & 3) * 16 + (d & 15)) * 8 + (k & 7);
  wh[idx] = h;
  wl[idx] = l;
}

// ------------- support = x @ W, split-bf16 (3 MFMA terms ~ fp32) -------------
__global__ __launch_bounds__(256) void k_support(const float* __restrict__ x,
                                                 const short* __restrict__ wh,
                                                 const short* __restrict__ wl,
                                                 float* __restrict__ sup) {
  int wave = threadIdx.x >> 6, lane = threadIdx.x & 63;
  int r0 = blockIdx.x * 64 + wave * 16;
  int arow = r0 + (lane & 15);
  if (arow >= NM) arow = NM - 1;
  int kb = (lane >> 4) * 8;
  f32x4 acc[8];
  #pragma unroll
  for (int dt = 0; dt < 8; ++dt)
    #pragma unroll
    for (int q = 0; q < 4; ++q) acc[dt][q] = 0.f;

  #pragma unroll
  for (int ks = 0; ks < 4; ++ks) {
    const float* ap = x + (size_t)arow * DD + ks * 32 + kb;
    float4 v0 = *(const float4*)ap;
    float4 v1 = *(const float4*)(ap + 4);
    float vv[8] = {v0.x, v0.y, v0.z, v0.w, v1.x, v1.y, v1.z, v1.w};
    s16x8 xh, xl;
    #pragma unroll
    for (int j = 0; j < 8; ++j) {
      short h = f2bf(vv[j]);
      xh[j] = h;
      xl[j] = f2bf(vv[j] - bf2f(h));
    }
    const short* bph = wh + ks * 4096 + lane * 8;
    const short* bpl = wl + ks * 4096 + lane * 8;
    #pragma unroll
    for (int dt = 0; dt < 8; ++dt) {
      s16x8 bh = *(const s16x8*)(bph + dt * 512);
      s16x8 bl = *(const s16x8*)(bpl + dt * 512);
      acc[dt] = MFMA(xh, bh, acc[dt], 0, 0, 0);
      acc[dt] = MFMA(xl, bh, acc[dt], 0, 0, 0);
      acc[dt] = MFMA(xh, bl, acc[dt], 0, 0, 0);
    }
  }
  int rg = (lane >> 4) * 4, cc = lane & 15;
  #pragma unroll
  for (int dt = 0; dt < 8; ++dt)
    #pragma unroll
    for (int q = 0; q < 4; ++q) {
      int rr = r0 + rg + q;
      if (rr < NM) sup[(size_t)rr * DD + dt * 16 + cc] = acc[dt][q];
    }
}

// ------------- fp16 row-major copy of sup_nodes for the SPMM gather -------------
__global__ __launch_bounds__(256) void k_suph(const float* __restrict__ sup,
                                              unsigned* __restrict__ suph) {
  int t = blockIdx.x * 256 + threadIdx.x;   // NN*64
  float2 f = *(const float2*)(sup + (size_t)t * 2);
  __half2 h = __floats2half2_rn(f.x, f.y);
  suph[t] = *(unsigned*)&h;
}

// ------------- pack support rows into bf16 B-fragment layout -------------
__global__ __launch_bounds__(256) void k_spack(const float* __restrict__ sup,
                                               short* __restrict__ bpk) {
  int t = blockIdx.x * 256 + threadIdx.x;   // 1,616,384
  int d = t & 127, ib = t >> 7;             // ib < 12628 (blocks of 8 rows)
  int rb = ib >> 2, g = ib & 3;
  s16x8 o;
  #pragma unroll
  for (int j = 0; j < 8; ++j) o[j] = f2bf(sup[(size_t)(ib * 8 + j) * DD + d]);
  *(s16x8*)(bpk + (size_t)((rb * 8 + (d >> 4)) * 64 + g * 16 + (d & 15)) * 8) = o;
}

// ------------- A1: block-private binning, no global atomics -------------
__global__ __launch_bounds__(256) void k_a1(const int* __restrict__ er,
                                            const int* __restrict__ ec,
                                            const float* __restrict__ ev,
                                            int* __restrict__ acnt,
                                            int2* __restrict__ a1buf) {
  __shared__ int cnt[SB];
  int t = threadIdx.x;
  if (t < SB) cnt[t] = 0;
  __syncthreads();
  int beg = blockIdx.x * 3125;
  size_t bbase = (size_t)blockIdx.x * SB;
  for (int e = beg + t; e < beg + 3125; e += 256) {
    int row = er[e];
    int2 rec = make_int2(ec[e] | ((row & 2047) << 17), __float_as_int(ev[e]));
    int s = row >> 11;
    int slot = atomicAdd(&cnt[s], 1);
    if (slot < BCAP) a1buf[(bbase + s) * BCAP + slot] = rec;
  }
  __syncthreads();
  if (t < SB) acnt[blockIdx.x * SB + t] = min(cnt[t], BCAP);
}

// ------------- per-super histogram + in-LDS exclusive scan -------------
__global__ __launch_bounds__(1024) void k_hist2(const int2* __restrict__ a1buf,
                                                const int* __restrict__ acnt,
                                                int* __restrict__ lexcl,
                                                int* __restrict__ tot) {
  __shared__ int hist[2048];
  __shared__ int ws2[1024];
  int t = threadIdx.x, s = blockIdx.x;
  hist[t] = 0; hist[t + 1024] = 0;
  __syncthreads();
  for (int i = t; i < A1BLKS * BCAP; i += 1024) {
    int b = i / BCAP, j = i - b * BCAP;
    if (j < acnt[b * SB + s]) {
      int rx = a1buf[((size_t)b * SB + s) * BCAP + j].x;
      atomicAdd(&hist[(rx >> 17) & 2047], 1);
    }
  }
  __syncthreads();
  int a = hist[2 * t], b2 = hist[2 * t + 1];
  int v = a + b2;
  ws2[t] = v;
  __syncthreads();
  for (int off = 1; off < 1024; off <<= 1) {
    int u = (t >= off) ? ws2[t - off] : 0;
    __syncthreads();
    ws2[t] += u;
    __syncthreads();
  }
  int excl = ws2[t] - v;
  lexcl[s * 2048 + 2 * t] = excl;
  lexcl[s * 2048 + 2 * t + 1] = excl + a;
  if (t == 1023) tot[s] = ws2[1023];
}

// ------------- tiny scan over 49 super totals -------------
__global__ void k_scan49(const int* __restrict__ tot, int* __restrict__ sbase,
                         int* __restrict__ offs) {
  if (threadIdx.x == 0) {
    int acc = 0;
    for (int s = 0; s < SB; ++s) { sbase[s] = acc; acc += tot[s]; }
    offs[NN] = NE;
  }
}

// ------------- S2b: exact CSR scatter, one block per super (L2-local window) -------------
__global__ __launch_bounds__(1024) void k_s2b(const int2* __restrict__ a1buf,
                                              const int* __restrict__ acnt,
                                              const int* __restrict__ lexcl,
                                              const int* __restrict__ sbase,
                                              int* __restrict__ offs,
                                              int2* __restrict__ pairs) {
  __shared__ int cur[2048];
  int t = threadIdx.x, s = blockIdx.x;
  int rbase = s << 11;
  int base = sbase[s];
  for (int l = t; l < 2048; l += 1024) {
    int o = base + lexcl[s * 2048 + l];
    cur[l] = o;
    int r = rbase + l;
    if (r < NN) offs[r] = o;
  }
  __syncthreads();
  for (int i = t; i < A1BLKS * BCAP; i += 1024) {
    int b = i / BCAP, j = i - b * BCAP;
    if (j < acnt[b * SB + s]) {
      int2 rec = a1buf[((size_t)b * SB + s) * BCAP + j];
      int pos = atomicAdd(&cur[(rec.x >> 17) & 2047], 1);
      pairs[pos] = make_int2(rec.x & 0x1FFFF, rec.y);
    }
  }
}

// ------------- U1: (A @ sup_comm)/rowsum -> out[0:NN); also dump bf16 A copy -------------
__global__ __launch_bounds__(256) void k_u1(const float* __restrict__ A,
                                            const short* __restrict__ bpk,
                                            float* __restrict__ out,
                                            short* __restrict__ abf) {
  __shared__ float rsh[128];
  int wave = threadIdx.x >> 6, lane = threadIdx.x & 63;
  int r0 = blockIdx.x * 128 + wave * 32;
  int kb = (lane >> 4) * 8;
  f32x4 acc[2][8];
  #pragma unroll
  for (int m = 0; m < 2; ++m)
    #pragma unroll
    for (int dt = 0; dt < 8; ++dt)
      #pragma unroll
      for (int q = 0; q < 4; ++q) acc[m][dt][q] = 0.f;
  float rs[2] = {0.f, 0.f};
  int row[2];
  #pragma unroll
  for (int m = 0; m < 2; ++m) {
    int r = r0 + m * 16 + (lane & 15);
    row[m] = (r < NN) ? r : NN - 1;
  }
  for (int ks = 0; ks < 32; ++ks) {
    s16x8 af[2];
    #pragma unroll
    for (int m = 0; m < 2; ++m) {
      const float* ap = A + (size_t)row[m] * NC + ks * 32 + kb;
      float4 v0 = *(const float4*)ap;
      float4 v1 = *(const float4*)(ap + 4);
      rs[m] += v0.x + v0.y + v0.z + v0.w + v1.x + v1.y + v1.z + v1.w;
      af[m][0] = f2bf(v0.x); af[m][1] = f2bf(v0.y);
      af[m][2] = f2bf(v0.z); af[m][3] = f2bf(v0.w);
      af[m][4] = f2bf(v1.x); af[m][5] = f2bf(v1.y);
      af[m][6] = f2bf(v1.z); af[m][7] = f2bf(v1.w);
      *(s16x8*)(abf + (size_t)row[m] * NC + ks * 32 + kb) = af[m];
    }
    const short* bp = bpk + (size_t)(3125 + ks) * 4096 + lane * 8;
    #pragma unroll
    for (int dt = 0; dt < 8; ++dt) {
      s16x8 b = *(const s16x8*)(bp + dt * 512);
      acc[0][dt] = MFMA(af[0], b, acc[0][dt], 0, 0, 0);
      acc[1][dt] = MFMA(af[1], b, acc[1][dt], 0, 0, 0);
    }
  }
  #pragma unroll
  for (int m = 0; m < 2; ++m) {
    float v = rs[m];
    v += __shfl_xor(v, 16);
    v += __shfl_xor(v, 32);
    if (lane < 16) rsh[wave * 32 + m * 16 + lane] = v;
  }
  __syncthreads();
  int rg = (lane >> 4) * 4, cc = lane & 15;
  #pragma unroll
  for (int m = 0; m < 2; ++m)
    #pragma unroll
    for (int q = 0; q < 4; ++q) {
      int wr = wave * 32 + m * 16 + rg + q;
      int r = blockIdx.x * 128 + wr;
      if (r < NN) {
        float inv = 1.f / rsh[wr];
        #pragma unroll
        for (int dt = 0; dt < 8; ++dt)
          out[(size_t)r * DD + dt * 16 + cc] = acc[m][dt][q] * inv;
      }
    }
}

// ------------- U2: A^T @ sup_nodes from bf16 abf copy (atomic reduce) -------------
__global__ __launch_bounds__(256) void k_u2(const short* __restrict__ abf,
                                            const short* __restrict__ bpk,
                                            float* __restrict__ u2,
                                            float* __restrict__ csum) {
  __shared__ short atile[2][128 * 40];   // [c_local][i] bf16, padded pitch 40
  int wave = threadIdx.x >> 6, lane = threadIdx.x & 63;
  int c0 = (blockIdx.x & 7) * 128;
  int s = blockIdx.x >> 3;            // 0..124, i-chunk of 800 rows
  int wc = wave * 32;
  f32x4 acc[2][8];
  #pragma unroll
  for (int m = 0; m < 2; ++m)
    #pragma unroll
    for (int dt = 0; dt < 8; ++dt)
      #pragma unroll
      for (int q = 0; q < 4; ++q) acc[m][dt][q] = 0.f;
  float cs[2] = {0.f, 0.f};
  int li = threadIdx.x >> 4;           // 0..15
  int lc = (threadIdx.x & 15) * 8;     // 0..120

  s16x8 rv[2];
  #pragma unroll
  for (int it = 0; it < 2; ++it)
    rv[it] = *(const s16x8*)(abf + (size_t)(s * 800 + it * 16 + li) * NC + c0 + lc);
  #pragma unroll
  for (int it = 0; it < 2; ++it)
    #pragma unroll
    for (int j = 0; j < 8; ++j)
      atile[0][(lc + j) * 40 + it * 16 + li] = rv[it][j];
  __syncthreads();

  for (int kk = 0; kk < 25; ++kk) {
    int p = kk & 1;
    if (kk < 24) {
      int i0n = s * 800 + (kk + 1) * 32;
      #pragma unroll
      for (int it = 0; it < 2; ++it)
        rv[it] = *(const s16x8*)(abf + (size_t)(i0n + it * 16 + li) * NC + c0 + lc);
    }
    s16x8 af[2];
    #pragma unroll
    for (int m = 0; m < 2; ++m) {
      af[m] = *(const s16x8*)(&atile[p][(wc + m * 16 + (lane & 15)) * 40 + (lane >> 4) * 8]);
      #pragma unroll
      for (int j = 0; j < 8; ++j) cs[m] += bf2f(af[m][j]);
    }
    if (kk < 24) {
      #pragma unroll
      for (int it = 0; it < 2; ++it)
        #pragma unroll
        for (int j = 0; j < 8; ++j)
          atile[p ^ 1][(lc + j) * 40 + it * 16 + li] = rv[it][j];
    }
    const short* bp = bpk + (size_t)(s * 25 + kk) * 4096 + lane * 8;
    #pragma unroll
    for (int dt = 0; dt < 8; ++dt) {
      s16x8 b = *(const s16x8*)(bp + dt * 512);
      acc[0][dt] = MFMA(af[0], b, acc[0][dt], 0, 0, 0);
      acc[1][dt] = MFMA(af[1], b, acc[1][dt], 0, 0, 0);
    }
    __syncthreads();
  }
  #pragma unroll
  for (int m = 0; m < 2; ++m) {
    float v = cs[m];
    v += __shfl_xor(v, 16);
    v += __shfl_xor(v, 32);
    if (lane < 16) atomicAdd(&csum[c0 + wc + m * 16 + lane], v);
  }
  int rg = (lane >> 4) * 4, cc = lane & 15;
  #pragma unroll
  for (int m = 0; m < 2; ++m)
    #pragma unroll
    for (int dt = 0; dt < 8; ++dt)
      #pragma unroll
      for (int q = 0; q < 4; ++q)
        atomicAdd(&u2[(size_t)(c0 + wc + m * 16 + rg + q) * DD + dt * 16 + cc],
                  acc[m][dt][q]);
}

// ------------- out2 = u2 / colsum -> out[NN:NM) -------------
__global__ __launch_bounds__(256) void k_out2(const float* __restrict__ u2,
                                              const float* __restrict__ csum,
                                              float* __restrict__ out) {
  int t = blockIdx.x * 256 + threadIdx.x;   // 131072
  int c = t >> 7;
  out[(size_t)(NN + c) * DD + (t & 127)] = u2[t] / csum[c];
}

// ------------- SPMM: one wave per row, fp16 gather, unrolled x4 -------------
__global__ __launch_bounds__(256) void k_spmm(const int* __restrict__ offs,
                                              const int2* __restrict__ pairs,
                                              const unsigned* __restrict__ suph,
                                              float* __restrict__ out) {
  int wave = threadIdx.x >> 6, lane = threadIdx.x & 63;
  int row = blockIdx.x * 4 + wave;   // grid 25000 -> rows exactly cover NN
  int beg = offs[row], end = offs[row + 1];
  float ax = 0.f, ay = 0.f;
  int e = beg;
  for (; e + 4 <= end; e += 4) {
    int2 p0 = pairs[e], p1 = pairs[e + 1], p2 = pairs[e + 2], p3 = pairs[e + 3];
    unsigned g0 = suph[(size_t)p0.x * 64 + lane];
    unsigned g1 = suph[(size_t)p1.x * 64 + lane];
    unsigned g2 = suph[(size_t)p2.x * 64 + lane];
    unsigned g3 = suph[(size_t)p3.x * 64 + lane];
    float2 v0 = __half22float2(*(__half2*)&g0);
    float2 v1 = __half22float2(*(__half2*)&g1);
    float2 v2 = __half22float2(*(__half2*)&g2);
    float2 v3 = __half22float2(*(__half2*)&g3);
    float c0 = __int_as_float(p0.y), c1 = __int_as_float(p1.y);
    float c2 = __int_as_float(p2.y), c3 = __int_as_float(p3.y);
    ax = fmaf(c0, v0.x, ax); ay = fmaf(c0, v0.y, ay);
    ax = fmaf(c1, v1.x, ax); ay = fmaf(c1, v1.y, ay);
    ax = fmaf(c2, v2.x, ax); ay = fmaf(c2, v2.y, ay);
    ax = fmaf(c3, v3.x, ax); ay = fmaf(c3, v3.y, ay);
  }
  for (; e < end; ++e) {
    int2 p = pairs[e];
    unsigned g = suph[(size_t)p.x * 64 + lane];
    float2 v = __half22float2(*(__half2*)&g);
    float c = __int_as_float(p.y);
    ax = fmaf(c, v.x, ax);
    ay = fmaf(c, v.y, ay);
  }
  float2* o = (float2*)(out + (size_t)row * DD);
  float2 c = o[lane];
  c.x += ax;
  c.y += ay;
  o[lane] = c;
}

extern "C" void kernel_launch(void* const* d_in, const int* in_sizes, int n_in,
                              void* d_out, int out_size, void* d_ws, size_t ws_size,
                              hipStream_t stream) {
  const float* x  = (const float*)d_in[0];
  const float* W  = (const float*)d_in[1];
  const float* A  = (const float*)d_in[2];
  const int*   er = (const int*)d_in[3];
  const int*   ec = (const int*)d_in[4];
  const float* ev = (const float*)d_in[5];
  float* out = (float*)d_out;

  char* ws = (char*)d_ws;
  size_t off = 0;
  auto alloc = [&](size_t bytes) -> void* {
    off = (off + 255) & ~(size_t)255;
    void* p = ws + off;
    off += bytes;
    return p;
  };
  float*    sup   = (float*)alloc((size_t)NM * DD * 4);     // 51.7 MB (a1buf overlay)
  short*    bpk   = (short*)alloc((size_t)NM * DD * 2);     // 25.9 MB
  unsigned* suphp = (unsigned*)alloc((size_t)NN * 64 * 4);  // 25.6 MB fp16 nodes
  short*    wh    = (short*)alloc(128 * 128 * 2);
  short*    wl    = (short*)alloc(128 * 128 * 2);
  // zero region (contiguous): u2acc | colsum
  float* u2    = (float*)alloc((size_t)NC * DD * 4);        // 131072 f
  float* csum  = (float*)alloc(NC * 4);                     // 1024 f
  short* abf   = (short*)alloc((size_t)NN * NC * 2);        // 204.8 MB bf16 A copy
  int*   acnt  = (int*)alloc((size_t)A1BLKS * SB * 4);      // 200 KB
  int*   lexcl = (int*)alloc((size_t)SB * 2048 * 4);        // 401 KB
  int*   tot   = (int*)alloc(SB * 4);
  int*   sbase = (int*)alloc(SB * 4);
  int*   offs  = (int*)alloc((NN + 1) * 4);
  int2*  pairs = (int2*)alloc((size_t)NE * 8);              // 25.6 MB
  int2*  a1buf = (int2*)sup;   // overlay: sup dead after k_spack; 48.2 MB <= 51.7 MB
  (void)ws_size; (void)in_sizes; (void)n_in; (void)out_size;

  const int ZN = NC * DD + NC;   // u2 | csum contiguous
  k_zero<<<dim3((ZN + 255) / 256), dim3(256), 0, stream>>>((int*)u2, ZN);
  k_wpack<<<dim3(64), dim3(256), 0, stream>>>(W, wh, wl);
  k_support<<<dim3(1579), dim3(256), 0, stream>>>(x, wh, wl, sup);
  k_suph<<<dim3(25000), dim3(256), 0, stream>>>(sup, suphp);
  k_spack<<<dim3(6314), dim3(256), 0, stream>>>(sup, bpk);
  // --- binning (sup is dead from here; a1buf reuses its storage) ---
  k_a1<<<dim3(A1BLKS), dim3(256), 0, stream>>>(er, ec, ev, acnt, a1buf);
  k_hist2<<<dim3(SB), dim3(1024), 0, stream>>>(a1buf, acnt, lexcl, tot);
  k_scan49<<<dim3(1), dim3(64), 0, stream>>>(tot, sbase, offs);
  k_s2b<<<dim3(SB), dim3(1024), 0, stream>>>(a1buf, acnt, lexcl, sbase, offs, pairs);
  // --- dense parts ---
  k_u1<<<dim3(782), dim3(256), 0, stream>>>(A, bpk, out, abf);
  k_u2<<<dim3(1000), dim3(256), 0, stream>>>(abf, bpk, u2, csum);
  k_out2<<<dim3(512), dim3(256), 0, stream>>>(u2, csum, out);
  k_spmm<<<dim3(25000), dim3(256), 0, stream>>>(offs, pairs, suphp, out);
}